// Round 8
// baseline (80.020 us; speedup 1.0000x reference)
//
#include <hip/hip_runtime.h>
#include <hip/hip_bf16.h>

// Problem constants (B=8, S=4096, D=128 per reference setup_inputs)
#define B_ 8
#define S_ 4096
#define D_ 128

typedef __attribute__((ext_vector_type(8))) short bf16x8;    // MFMA A/B frag (4 VGPRs)
typedef __attribute__((ext_vector_type(16))) float f32x16;   // 32x32 MFMA C/D frag
typedef __attribute__((ext_vector_type(4))) unsigned u32x4;

// f32 -> bf16 round-to-nearest-even
static __device__ __forceinline__ unsigned short f2bf(float x) {
    unsigned u = __float_as_uint(x);
    u += 0x7fffu + ((u >> 16) & 1u);
    return (unsigned short)(u >> 16);
}

// async global -> LDS, 16 bytes per lane (dest = wave-uniform base + lane*16)
typedef const __attribute__((address_space(1))) unsigned int* gas_ptr;
typedef __attribute__((address_space(3))) unsigned int* las_ptr;
static __device__ __forceinline__ void load_lds16(const unsigned short* g, unsigned short* l) {
    __builtin_amdgcn_global_load_lds((gas_ptr)(const void*)g, (las_ptr)(void*)l, 16, 0, 0);
}

#define WAIT_VMCNT_8 do { asm volatile("s_waitcnt vmcnt(8)" ::: "memory"); \
                          __builtin_amdgcn_sched_barrier(0); } while (0)
#define WAIT_VMCNT_0 do { asm volatile("s_waitcnt vmcnt(0)" ::: "memory"); \
                          __builtin_amdgcn_sched_barrier(0); } while (0)
#define BARRIER      do { __builtin_amdgcn_s_barrier(); \
                          __builtin_amdgcn_sched_barrier(0); } while (0)

// ---------------------------------------------------------------------------
// Fused prep: [0,2048) RoPE Q,K -> bf16 ; [2048,6144) zero d_out ;
//             [6144,6656) V transpose -> bf16
// ---------------------------------------------------------------------------
__global__ __launch_bounds__(256) void prep(const float* __restrict__ Q,
                                            const float* __restrict__ K,
                                            const float* __restrict__ V,
                                            unsigned short* __restrict__ Qr,
                                            unsigned short* __restrict__ Kr,
                                            unsigned short* __restrict__ Vt,
                                            float4* __restrict__ Oz) {
    __shared__ unsigned short tile[64][130];
    const int bid = blockIdx.x;
    if (bid < 2048) {
        int e = bid * 256 + threadIdx.x;          // 0 .. 8*4096*16-1
        int t = e & 15;
        int s = (e >> 4) & (S_ - 1);
        int b = e >> 16;
        size_t base = ((size_t)(b * S_ + s)) * D_;
        int d0 = t * 4;
        float qa[4], qb[4], ka[4], kb[4];
        *(float4*)qa = *(const float4*)(Q + base + d0);
        *(float4*)qb = *(const float4*)(Q + base + d0 + 64);
        *(float4*)ka = *(const float4*)(K + base + d0);
        *(float4*)kb = *(const float4*)(K + base + d0 + 64);
        unsigned short ql[4], qh[4], kl[4], kh[4];
        #pragma unroll
        for (int j = 0; j < 4; ++j) {
            float invf = exp2f(-0.20762050f * (float)(d0 + j));   // 10000^{-(d0+j)/64}
            float ang = (float)s * invf;
            float sn, cs;
            __sincosf(ang, &sn, &cs);
            ql[j] = f2bf(qa[j] * cs - qb[j] * sn);
            qh[j] = f2bf(qb[j] * cs + qa[j] * sn);
            kl[j] = f2bf(ka[j] * cs - kb[j] * sn);
            kh[j] = f2bf(kb[j] * cs + ka[j] * sn);
        }
        *reinterpret_cast<ushort4*>(Qr + base + d0)      = ushort4{ql[0], ql[1], ql[2], ql[3]};
        *reinterpret_cast<ushort4*>(Qr + base + d0 + 64) = ushort4{qh[0], qh[1], qh[2], qh[3]};
        *reinterpret_cast<ushort4*>(Kr + base + d0)      = ushort4{kl[0], kl[1], kl[2], kl[3]};
        *reinterpret_cast<ushort4*>(Kr + base + d0 + 64) = ushort4{kh[0], kh[1], kh[2], kh[3]};
    } else if (bid < 6144) {
        Oz[(size_t)(bid - 2048) * 256 + threadIdx.x] = float4{0.f, 0.f, 0.f, 0.f};
    } else {
        int b2 = bid - 6144;                      // 0..511
        int b  = b2 >> 6;
        int t0 = (b2 & 63) * 64;
        int tid = threadIdx.x;
        #pragma unroll
        for (int it = 0; it < 32; ++it) {
            int e = it * 256 + tid;
            int tl = e >> 7, d = e & 127;
            tile[tl][d] = f2bf(V[((size_t)(b * S_ + t0 + tl)) * D_ + d]);
        }
        __syncthreads();
        #pragma unroll
        for (int it = 0; it < 32; ++it) {
            int e = it * 256 + tid;
            int d = e >> 6, tl = e & 63;
            Vt[((size_t)(b * D_ + d)) * S_ + t0 + tl] = tile[tl][d];
        }
    }
}

// ---------------------------------------------------------------------------
// Causal no-softmax attention; 32x32x16 MFMA; r6 sync skeleton (proven).
//   512 blocks = 8 batches x 64 chunks of 16-17 work items.
//   Work item w in [0,1056): q-tile qi owns [qi*(qi+1),(qi+1)*(qi+2)),
//   kt = w - qi*(qi+1) in [0, 2qi+2). BM=128 (4 waves x 32 rows), BN=64.
//   K and V double-buffered (64KB LDS). Per iter:
//     vmcnt(8) [tile w landed; w+1 in flight] + bar | QK^T | mask |
//     in-reg transpose | PV | bar | stage tile w+2 into freed buf | flush?
// MFMA 32x32x16 bf16 layouts (h = lane>>5, m = lane&31):
//   A: lane holds A[row=m][k=8h+j]; B: B[k=8h+j][col=m]
//   C/D: lane,reg r holds D[row=(r&3)+8*(r>>2)+4h][col=m], r=0..15
//   E^T = mfma(K,Q): row=t, col=s; lane holds 16 t-values of one s-column.
//   Transpose to PV A-frags: 16 cvt_pk + 8 permlane32_swap
//   (permlane32_swap(a,b): a'={a.lo,b.lo}, b'={a.hi,b.hi} — HW-verified r4-r6).
// ---------------------------------------------------------------------------
__global__ __launch_bounds__(256, 2) void attn(const unsigned short* __restrict__ Qr,
                                               const unsigned short* __restrict__ Kr,
                                               const unsigned short* __restrict__ Vt,
                                               float* __restrict__ Out) {
    __shared__ unsigned short Kb[2][64 * 128];   // [t][d] swizzled chunks, 2x16KB
    __shared__ unsigned short Vb[2][128 * 64];   // [d][t] swizzled chunks, 2x16KB

    const int r  = blockIdx.x;
    const int b  = r & 7;
    const int j  = r >> 3;                        // chunk 0..63 within batch
    const int w0 = (j * 33) >> 1;                 // [w0,w1): 16 or 17 items
    const int w1 = ((j + 1) * 33) >> 1;

    int qi = 0;
    while ((qi + 1) * (qi + 2) <= w0) ++qi;
    int kt = w0 - qi * (qi + 1);

    const int tid = threadIdx.x;
    const int wv = tid >> 6;                      // wave 0..3 (owns 32 q-rows)
    const int l  = tid & 63;
    const int h  = l >> 5;                        // k-half 0..1
    const int m  = l & 31;                        // row/col within 32

    bf16x8 qf[8];                                 // Q B-frags: d = 16ks + 8h + j
    auto hoistQ = [&](int qq) {
        const unsigned short* qp =
            Qr + ((size_t)(b * S_ + qq * 128 + wv * 32 + m)) * D_ + 8 * h;
        #pragma unroll
        for (int ks = 0; ks < 8; ++ks)
            qf[ks] = *reinterpret_cast<const bf16x8*>(qp + ks * 16);
    };

    f32x16 o[4];                                  // O tiles: d-tile df, 16 s-rows/lane
    auto zeroO = [&]() {
        #pragma unroll
        for (int df = 0; df < 4; ++df)
            #pragma unroll
            for (int rr = 0; rr < 16; ++rr) o[df][rr] = 0.f;
    };
    auto flush = [&](int qq) {
        #pragma unroll
        for (int df = 0; df < 4; ++df)
            #pragma unroll
            for (int rr = 0; rr < 16; ++rr) {
                int srow = qq * 128 + wv * 32 + (rr & 3) + 8 * (rr >> 2) + 4 * h;
                atomicAdd(&Out[((size_t)(b * S_ + srow)) * D_ + df * 32 + m],
                          o[df][rr]);
            }
    };

    // K LDS chunk (t,c) holds global chunk (t, c^(t&15)); V chunk (d,c): c^(d&7)
    auto stage = [&](int bufs, int ktg) {
        const unsigned short* kbase = Kr + ((size_t)(b * S_ + ktg * 64)) * D_;
        #pragma unroll
        for (int i = 0; i < 4; ++i) {
            int ci = i * 256 + tid;
            int t = ci >> 4, c = ci & 15;
            load_lds16(kbase + t * D_ + ((c ^ (t & 15)) * 8), &Kb[bufs][ci * 8]);
        }
        const unsigned short* vbase = Vt + (size_t)b * D_ * S_ + ktg * 64;
        #pragma unroll
        for (int i = 0; i < 4; ++i) {
            int ci = i * 256 + tid;
            int d = ci >> 3, c = ci & 7;
            load_lds16(vbase + (size_t)d * S_ + ((c ^ (d & 7)) * 8), &Vb[bufs][ci * 8]);
        }
    };

    hoistQ(qi);
    zeroO();
    stage(0, kt);                                  // tile w0       (8 entries)
    {
        int k1 = kt + 1;
        if (k1 == 2 * qi + 2) k1 = 0;              // next item may start next q-tile
        stage(1, k1);                              // tile w0+1     (16 outstanding)
    }

    int buf = 0;

    for (int w = w0; w < w1; ++w) {
        if (w == w1 - 1) { WAIT_VMCNT_0; }         // last: nothing behind
        else             { WAIT_VMCNT_8; }         // tile w landed; w+1 in flight
        BARRIER;

        // ---- E^T = K.Q^T: e[tf] reg rr -> t = kt*64+tf*32+(rr&3)+8*(rr>>2)+4h,
        //      s = qi*128+wv*32+m
        f32x16 e[2];
        #pragma unroll
        for (int tf = 0; tf < 2; ++tf)
            #pragma unroll
            for (int rr = 0; rr < 16; ++rr) e[tf][rr] = 0.f;
        __builtin_amdgcn_s_setprio(1);
        #pragma unroll
        for (int ks = 0; ks < 8; ++ks) {
            #pragma unroll
            for (int tf = 0; tf < 2; ++tf) {
                const bf16x8 kf = *reinterpret_cast<const bf16x8*>(
                    &Kb[buf][(tf * 32 + m) * 128 + (((2 * ks + h) ^ (m & 15)) * 8)]);
                e[tf] = __builtin_amdgcn_mfma_f32_32x32x16_bf16(kf, qf[ks], e[tf], 0, 0, 0);
            }
        }
        __builtin_amdgcn_s_setprio(0);

        // ---- causal mask (diagonal-straddling tiles: kt in {2qi, 2qi+1})
        if (kt >= 2 * qi) {
            int s_glob = qi * 128 + wv * 32 + m;
            #pragma unroll
            for (int tf = 0; tf < 2; ++tf)
                #pragma unroll
                for (int rr = 0; rr < 16; ++rr) {
                    int t_glob = kt * 64 + tf * 32 + (rr & 3) + 8 * (rr >> 2) + 4 * h;
                    if (t_glob > s_glob) e[tf][rr] = 0.f;
                }
        }

        // ---- E -> P A-frags in-register: 16 cvt_pk + 8 permlane32_swap ----
        bf16x8 pf[4];                              // k-step kp: t = 16kp + 8h + j
        #pragma unroll
        for (int tf = 0; tf < 2; ++tf) {
            unsigned wd[8];
            #pragma unroll
            for (int i = 0; i < 8; ++i)
                asm("v_cvt_pk_bf16_f32 %0, %1, %2"
                    : "=v"(wd[i]) : "v"(e[tf][2 * i]), "v"(e[tf][2 * i + 1]));
            asm("v_permlane32_swap_b32 %0, %1" : "+v"(wd[0]), "+v"(wd[2]));
            asm("v_permlane32_swap_b32 %0, %1" : "+v"(wd[1]), "+v"(wd[3]));
            asm("v_permlane32_swap_b32 %0, %1" : "+v"(wd[4]), "+v"(wd[6]));
            asm("v_permlane32_swap_b32 %0, %1" : "+v"(wd[5]), "+v"(wd[7]));
            pf[2 * tf]     = __builtin_bit_cast(bf16x8, u32x4{wd[0], wd[1], wd[2], wd[3]});
            pf[2 * tf + 1] = __builtin_bit_cast(bf16x8, u32x4{wd[4], wd[5], wd[6], wd[7]});
        }

        // ---- O += P.V ----
        __builtin_amdgcn_s_setprio(1);
        #pragma unroll
        for (int df = 0; df < 4; ++df) {
            #pragma unroll
            for (int kp = 0; kp < 4; ++kp) {
                const bf16x8 vf = *reinterpret_cast<const bf16x8*>(
                    &Vb[buf][(df * 32 + m) * 64 + (((2 * kp + h) ^ (m & 7)) * 8)]);
                o[df] = __builtin_amdgcn_mfma_f32_32x32x16_bf16(pf[kp], vf, o[df], 0, 0, 0);
            }
        }
        __builtin_amdgcn_s_setprio(0);

        BARRIER;                                   // all waves done reading buf

        if (w + 2 < w1) {                          // stage tile w+2 into freed buf
            int k2 = kt + 2;
            const int lim = 2 * qi + 2;
            if (k2 >= lim) k2 -= lim;              // next q-tile's kt (K addr = kt only)
            stage(buf, k2);
        }

        buf ^= 1;
        ++kt;
        if (kt == 2 * qi + 2 && w + 1 < w1) {      // q-tile crossing mid-chunk
            flush(qi);                             // atomics AFTER stage -> youngest
            zeroO();
            ++qi;
            kt = 0;
            hoistQ(qi);                            // rare over-wait next iter; safe
        }
    }
    flush(qi);
}

// ---------------------------------------------------------------------------
extern "C" void kernel_launch(void* const* d_in, const int* in_sizes, int n_in,
                              void* d_out, int out_size, void* d_ws, size_t ws_size,
                              hipStream_t stream) {
    const float* Q = (const float*)d_in[0];
    const float* K = (const float*)d_in[1];
    const float* V = (const float*)d_in[2];

    unsigned short* Qr = (unsigned short*)d_ws;
    unsigned short* Kr = Qr + (size_t)B_ * S_ * D_;
    unsigned short* Vt = Kr + (size_t)B_ * S_ * D_;

    prep<<<6656, 256, 0, stream>>>(Q, K, V, Qr, Kr, Vt, (float4*)d_out);
    attn<<<512, 256, 0, stream>>>(Qr, Kr, Vt, (float*)d_out);
}